// Round 1
// 705.311 us; speedup vs baseline: 1.0339x; 1.0339x over previous
//
#include <hip/hip_runtime.h>

// ParabolicPool2D: out[b,c,i,j] = max_{u,v} f[b,c,2i+u-3,2j+v-3] + hu[u] + hu[v]
// (max-plus separable). f: (16,128,256,256) fp32 -> out: (16,128,128,128) fp32.
// v2 changes vs 729us baseline:
//  - TH 32->16: LDS 30.9KB -> 16.6KB => 8 blocks/CU (32 waves, was 20) for latency hiding
//  - phase-1 loads register-staged 3-deep, unconditional (clamped addr), -inf selected at
//    LDS-write => 3 loads in flight per wave instead of load->vmcnt(0)->ds_write serialization
//  - hu[] computed under the load shadow
//  - bijective XCD swizzle: each XCD gets contiguous planes; vertical strip neighbors run
//    back-to-back on the same XCD => y-halo rows hit that XCD's L2

#define KS 7
#define PAD 3
#define H 256
#define W 256
#define HO 128
#define WO 128
#define TH 16            // output tile rows per block
#define TW 32            // output tile cols per block
#define ROWS 37          // input rows needed: 2*TH+5
#define NF4 18           // float4 per input row
#define COLS 72          // floats per LDS row (covers needed 69)
#define SSTRIDE 76       // 76 % 32 == 12 -> phase-2 b128 reads conflict-free
#define GSTRIDE 36
#define NITEMS (ROWS * NF4)   // 666 float4 loads per block

__global__ __launch_bounds__(256, 8)
void pp_kernel(const float* __restrict__ f, const float* __restrict__ tptr,
               float* __restrict__ out) {
    __shared__ __align__(16) float sin_[ROWS * SSTRIDE];   // 11248 B
    __shared__ __align__(16) float g_[ROWS * GSTRIDE];     //  5328 B (16.6 KB total)

    const int tid = threadIdx.x;
    const int bid = blockIdx.x;
    // 65536 blocks, 8 XCDs, q=8192 exactly: lid = (bid%8)*8192 + bid/8 is bijective.
    // XCD k processes logical ids [8192k, 8192(k+1)) in order -> planes [256k,256k+256).
    const int lid   = (bid & 7) * 8192 + (bid >> 3);
    const int plane = lid >> 5;          // b*128 + c
    const int t5    = lid & 31;          // 32 tiles/plane: 4 col-tiles x 8 row-strips,
    const int i0    = (t5 & 7) * TH;     // row-strip fastest -> vertical neighbors adjacent
    const int j0    = (t5 >> 3) * TW;

    const int gy0 = 2 * i0 - 3;
    const int gx0 = 2 * j0 - 4;          // multiple of 4: float4s fully in- or out-of-bounds
    const float* __restrict__ fplane = f + (size_t)plane * (H * W);
    const float NEG = -__builtin_inff();

    // ---- Phase 1a: issue all 3 global loads (clamped, unconditional) ----
    float4 raw[3];
    int lofs[3];
    bool keep[3], inb[3];
#pragma unroll
    for (int k = 0; k < 3; ++k) {
        const int idx = tid + 256 * k;
        const int r   = idx / NF4;
        const int c4  = idx - r * NF4;
        const int gy  = gy0 + r;
        const int gx  = gx0 + 4 * c4;
        keep[k] = (idx < NITEMS);
        inb[k]  = keep[k] & (gy >= 0) & (gy < H) & (gx >= 0) & (gx < W);
        const int cy = min(max(gy, 0), H - 1);
        const int cx = min(max(gx, 0), W - 4);
        raw[k]  = *(const float4*)(fplane + cy * W + cx);   // always valid address
        lofs[k] = r * SSTRIDE + 4 * c4;
    }

    // hu[] computed while loads are in flight
    const float tv = tptr[0];
    float hu[KS];
#pragma unroll
    for (int v = 0; v < KS; ++v) {
        const float z = (float)(v - PAD);
        hu[v] = -(z * z) / (4.0f * tv);
    }

    // ---- Phase 1b: LDS writes (compiler emits counted vmcnt: 3 loads stay in flight) ----
#pragma unroll
    for (int k = 0; k < 3; ++k) {
        if (keep[k]) {
            float4 val = inb[k] ? raw[k] : make_float4(NEG, NEG, NEG, NEG);
            *(float4*)(&sin_[lofs[k]]) = val;
        }
    }
    __syncthreads();

    // ---- Phase 2: horizontal max-plus: g[y][j] = max_v sin[y][2j+1+v] + hu[v] ----
    {
        const int q  = tid & 7;        // run of 4 g-columns
        const int yb = tid >> 3;       // 0..31
        const int jr = q * 4;
#pragma unroll 1
        for (int y = yb; y < ROWS; y += 32) {    // yb<5 does rows 32..36
            const float* row = &sin_[y * SSTRIDE + 2 * jr];   // 16B-aligned
            const float4 w0 = *(const float4*)(row);
            const float4 w1 = *(const float4*)(row + 4);
            const float4 w2 = *(const float4*)(row + 8);
            const float4 w3 = *(const float4*)(row + 12);
            const float s[16] = {w0.x, w0.y, w0.z, w0.w, w1.x, w1.y, w1.z, w1.w,
                                 w2.x, w2.y, w2.z, w2.w, w3.x, w3.y, w3.z, w3.w};
            float4 gv;
            float* gp = (float*)&gv;
#pragma unroll
            for (int jj = 0; jj < 4; ++jj) {
                float m = s[2 * jj + 1] + hu[0];
#pragma unroll
                for (int v = 1; v < KS; ++v)
                    m = fmaxf(m, s[2 * jj + 1 + v] + hu[v]);
                gp[jj] = m;
            }
            *(float4*)(&g_[y * GSTRIDE + jr]) = gv;
        }
    }
    __syncthreads();

    // ---- Phase 3: vertical max-plus + coalesced store (2 rows/thread) ----
    {
        const int j  = tid & 31;
        const int ir = (tid >> 5) * 2;       // 0,2,...,14
        float col[9];
#pragma unroll
        for (int k = 0; k < 9; ++k)
            col[k] = g_[(2 * ir + k) * GSTRIDE + j];
        float m0 = col[0] + hu[0];
        float m1 = col[2] + hu[0];
#pragma unroll
        for (int u = 1; u < KS; ++u) {
            m0 = fmaxf(m0, col[u]     + hu[u]);
            m1 = fmaxf(m1, col[u + 2] + hu[u]);
        }
        float* __restrict__ oplane = out + (size_t)plane * (HO * WO);
        oplane[(size_t)(i0 + ir)     * WO + (j0 + j)] = m0;
        oplane[(size_t)(i0 + ir + 1) * WO + (j0 + j)] = m1;
    }
}

extern "C" void kernel_launch(void* const* d_in, const int* in_sizes, int n_in,
                              void* d_out, int out_size, void* d_ws, size_t ws_size,
                              hipStream_t stream) {
    const float* f = (const float*)d_in[0];
    const float* t = (const float*)d_in[1];
    float* out = (float*)d_out;
    // 2048 planes x 32 tiles (4x8) each
    pp_kernel<<<dim3(2048 * 32), dim3(256), 0, stream>>>(f, t, out);
}